// Round 10
// baseline (174.471 us; speedup 1.0000x reference)
//
#include <hip/hip_runtime.h>
#include <cmath>

// B=1, H=64, W=128, C=256, 8 heads x 32 dim, 7x7 window.
#define HH 64
#define WW 128
#define CC 256
#define NHEAD 8
#define HDIM 32
#define NPIX (HH*WW)       // 8192
#define QKV_N (3*CC)       // 768
#define NBLK 1024u         // co-resident: LDS 36.7KB->4/CU, launch_bounds(256,4)->VGPR<=128

#define KSLOT 248
#define LDK   40
#define VSLOT 264

typedef __attribute__((ext_vector_type(8))) short short8v;  // 8 bf16
typedef __attribute__((ext_vector_type(4))) short short4v;  // 4 bf16
typedef __attribute__((ext_vector_type(4))) float f32x4;
typedef unsigned int u32;

__device__ __forceinline__ short f2bf(float f) {
    unsigned int u = __builtin_bit_cast(unsigned int, f);
    u += 0x7fffu + ((u >> 16) & 1u);
    return (short)(u >> 16);
}

// ---------------------------------------------------------------------------
// Grid barrier v3. R8 post-mortem: a RELAXED plain load polls the LOCAL XCD
// L2, which is never invalidated by a remote release -> stale-spin until
// chance eviction (~85us idle). Fix: poll with a relaxed atomic RMW
// (fetch_add 0) -- RMWs execute at the device coherence point, coherent
// WITHOUT invalidates. One ACQUIRE at exit does the cache maintenance
// (R8 proved that part: correctness held). Flag replicated 8x128B so only
// 128 spinners share a line; arrivals on 8 spaced sub-counters.
// Counters monotonic, zeroed by a 2176B hipMemsetAsync node per launch.
// ---------------------------------------------------------------------------
__device__ __forceinline__ void grid_sync(u32* syncb, u32 bar, int bid)
{
    __syncthreads();
    if (threadIdx.x == 0) {
        u32* sub   = syncb + (bid & 7) * 32;          // 8 x 128B
        u32* top   = syncb + 8 * 32;
        u32* flagv = syncb + (9 + (bid & 7)) * 32;    // 8 replicas x 128B
        u32 prev = __hip_atomic_fetch_add(sub, 1u, __ATOMIC_ACQ_REL,
                                          __HIP_MEMORY_SCOPE_AGENT);
        if (prev == bar * (NBLK / 8u) - 1u) {
            u32 p2 = __hip_atomic_fetch_add(top, 1u, __ATOMIC_ACQ_REL,
                                            __HIP_MEMORY_SCOPE_AGENT);
            if (p2 == bar * 8u - 1u) {
#pragma unroll
                for (int r = 0; r < 8; ++r)
                    __hip_atomic_store(syncb + (9 + r) * 32, bar,
                                       __ATOMIC_RELEASE, __HIP_MEMORY_SCOPE_AGENT);
            }
        }
        while (__hip_atomic_fetch_add(flagv, 0u, __ATOMIC_RELAXED,
                                      __HIP_MEMORY_SCOPE_AGENT) < bar)
            __builtin_amdgcn_s_sleep(32);
        (void)__hip_atomic_load(flagv, __ATOMIC_ACQUIRE,
                                __HIP_MEMORY_SCOPE_AGENT);   // one inv
    }
    __syncthreads();
}

// ---------------------------------------------------------------------------
// Phase 0 unit: weight transpose tile (R9 prep_w body).
// ---------------------------------------------------------------------------
__device__ __forceinline__ void prep_unit(float* ldsf, int idx,
    const float* __restrict__ w_qkv, const float* __restrict__ w_proj,
    short* __restrict__ wq_t, short* __restrict__ wp_t)
{
    float (*tile)[33] = reinterpret_cast<float(*)[33]>(ldsf);
    const float* src; short* dst; int N;
    if (idx < 192) { src = w_qkv;  dst = wq_t; N = QKV_N; }
    else { idx -= 192; src = w_proj; dst = wp_t; N = CC; }
    const int nbx = N / 32;
    const int bn = (idx % nbx) * 32;
    const int bk = (idx / nbx) * 32;
    const int tx = threadIdx.x & 31, ty = threadIdx.x >> 5;
#pragma unroll
    for (int i = 0; i < 32; i += 8)
        tile[ty + i][tx] = src[(size_t)(bk + ty + i) * N + bn + tx];
    __syncthreads();
#pragma unroll
    for (int i = 0; i < 32; i += 8)
        dst[(size_t)(bn + ty + i) * CC + bk + tx] = f2bf(tile[tx][ty + i]);
}

// ---------------------------------------------------------------------------
// Phase 1 tile: QKV GEMM 64x128 (R9 gemm_qkv body, verbatim math).
// ---------------------------------------------------------------------------
__device__ __forceinline__ void qkv_tile(short* lds,
    const float* __restrict__ A, const short* __restrict__ Bt,
    const float* __restrict__ bias, short* __restrict__ Cp, int bm, int bn)
{
    short* As = lds;                 // 64*40 shorts, padded rows
    short* Bs = lds + 64 * 40;       // [2][128*32] linear

    const int tid = threadIdx.x, lane = tid & 63, wave = tid >> 6;
    const int wm0 = (wave >> 1) * 32, wn0 = (wave & 1) * 64;
    const int l15 = lane & 15, l4 = lane >> 4;
    const int arow = tid >> 2, akoff = (tid & 3) * 8;

    f32x4 acc[2][4];
#pragma unroll
    for (int i = 0; i < 2; ++i)
#pragma unroll
        for (int j = 0; j < 4; ++j) acc[i][j] = (f32x4){0.f, 0.f, 0.f, 0.f};

    auto stageB = [&](int buf, int t) {
#pragma unroll
        for (int i = 0; i < 2; ++i) {
            const int g = tid + 256 * i;
            const int row = g >> 2, gr = g & 3;
            __builtin_amdgcn_global_load_lds(
                (const __attribute__((address_space(1))) u32*)
                    (Bt + (size_t)(bn + row) * CC + t * 32 + ((gr ^ (row & 3)) * 8)),
                (__attribute__((address_space(3))) u32*)&Bs[buf * 128 * 32 + g * 8],
                16, 0, 0);
        }
    };

    float4 a0, a1;
    {
        const float* p = A + (size_t)(bm + arow) * CC + akoff;
        a0 = *(const float4*)p; a1 = *(const float4*)(p + 4);
    }
    stageB(0, 0);

    for (int t = 0; t < 8; ++t) {
        const int cur = t & 1;
        __syncthreads();
        {
            short8v w;
            w[0] = f2bf(a0.x); w[1] = f2bf(a0.y); w[2] = f2bf(a0.z); w[3] = f2bf(a0.w);
            w[4] = f2bf(a1.x); w[5] = f2bf(a1.y); w[6] = f2bf(a1.z); w[7] = f2bf(a1.w);
            *(short8v*)&As[arow * 40 + akoff] = w;
        }
        __syncthreads();
        if (t + 1 < 8) {
            const float* p = A + (size_t)(bm + arow) * CC + (t + 1) * 32 + akoff;
            a0 = *(const float4*)p; a1 = *(const float4*)(p + 4);
            stageB(cur ^ 1, t + 1);
        }

        short8v af[2], bf[4];
#pragma unroll
        for (int fm = 0; fm < 2; ++fm)
            af[fm] = *(const short8v*)&As[(wm0 + fm * 16 + l15) * 40 + l4 * 8];
#pragma unroll
        for (int fn = 0; fn < 4; ++fn) {
            const int row = wn0 + fn * 16 + l15;
            bf[fn] = *(const short8v*)&Bs[cur * 128 * 32 + row * 32 + ((l4 ^ (row & 3)) * 8)];
        }
#pragma unroll
        for (int fm = 0; fm < 2; ++fm)
#pragma unroll
            for (int fn = 0; fn < 4; ++fn)
                acc[fm][fn] = __builtin_amdgcn_mfma_f32_16x16x32_bf16(
                    af[fm], bf[fn], acc[fm][fn], 0, 0, 0);
    }

    const int col0 = bn + wn0 + l15;
    const int row0 = bm + wm0 + l4 * 4;
#pragma unroll
    for (int fn = 0; fn < 4; ++fn) {
        const int cc = col0 + fn * 16;
        const float bv = bias[cc];
#pragma unroll
        for (int fm = 0; fm < 2; ++fm)
#pragma unroll
            for (int r = 0; r < 4; ++r) {
                const int rr = row0 + fm * 16 + r;
                Cp[((size_t)(cc >> 5) * NPIX + rr) * HDIM + (cc & 31)] =
                    f2bf(acc[fm][fn][r] + bv);
            }
    }
}

// ---------------------------------------------------------------------------
// Phase 3 tile: proj GEMM 64x128 (R9 gemm_proj body, verbatim math).
// ---------------------------------------------------------------------------
__device__ __forceinline__ void proj_tile(short* lds,
    const short* __restrict__ A, const short* __restrict__ Bt,
    const float* __restrict__ bias, float* __restrict__ C, int bm, int bn)
{
    short* As = lds;                 // [2][64*32]
    short* Bs = lds + 2 * 64 * 32;   // [2][128*32]

    const int tid = threadIdx.x, lane = tid & 63, wave = tid >> 6;
    const int wm0 = (wave >> 1) * 32, wn0 = (wave & 1) * 64;
    const int l15 = lane & 15, l4 = lane >> 4;

    f32x4 acc[2][4];
#pragma unroll
    for (int i = 0; i < 2; ++i)
#pragma unroll
        for (int j = 0; j < 4; ++j) acc[i][j] = (f32x4){0.f, 0.f, 0.f, 0.f};

    auto stage = [&](int buf, int t) {
        {
            const int row = tid >> 2, gr = tid & 3;
            __builtin_amdgcn_global_load_lds(
                (const __attribute__((address_space(1))) u32*)
                    (A + (size_t)(bm + row) * CC + t * 32 + ((gr ^ (row & 3)) * 8)),
                (__attribute__((address_space(3))) u32*)&As[buf * 64 * 32 + tid * 8],
                16, 0, 0);
        }
#pragma unroll
        for (int i = 0; i < 2; ++i) {
            const int g = tid + 256 * i;
            const int row = g >> 2, gr = g & 3;
            __builtin_amdgcn_global_load_lds(
                (const __attribute__((address_space(1))) u32*)
                    (Bt + (size_t)(bn + row) * CC + t * 32 + ((gr ^ (row & 3)) * 8)),
                (__attribute__((address_space(3))) u32*)&Bs[buf * 128 * 32 + g * 8],
                16, 0, 0);
        }
    };

    stage(0, 0);

    for (int t = 0; t < 8; ++t) {
        const int cur = t & 1;
        __syncthreads();
        if (t + 1 < 8) stage(cur ^ 1, t + 1);

        short8v af[2], bf[4];
#pragma unroll
        for (int fm = 0; fm < 2; ++fm) {
            const int row = wm0 + fm * 16 + l15;
            af[fm] = *(const short8v*)&As[cur * 64 * 32 + row * 32 + ((l4 ^ (row & 3)) * 8)];
        }
#pragma unroll
        for (int fn = 0; fn < 4; ++fn) {
            const int row = wn0 + fn * 16 + l15;
            bf[fn] = *(const short8v*)&Bs[cur * 128 * 32 + row * 32 + ((l4 ^ (row & 3)) * 8)];
        }
#pragma unroll
        for (int fm = 0; fm < 2; ++fm)
#pragma unroll
            for (int fn = 0; fn < 4; ++fn)
                acc[fm][fn] = __builtin_amdgcn_mfma_f32_16x16x32_bf16(
                    af[fm], bf[fn], acc[fm][fn], 0, 0, 0);
    }

    const int col0 = bn + wn0 + l15;
    const int row0 = bm + wm0 + l4 * 4;
#pragma unroll
    for (int fn = 0; fn < 4; ++fn) {
        const float bv = bias[col0 + fn * 16];
#pragma unroll
        for (int fm = 0; fm < 2; ++fm)
#pragma unroll
            for (int r = 0; r < 4; ++r)
                C[(size_t)(row0 + fm * 16 + r) * CC + col0 + fn * 16] =
                    acc[fm][fn][r] + bv;
    }
}

// ---------------------------------------------------------------------------
// Phase 2 tile: neighborhood attention (R9 na_mfma body, verbatim math).
// ---------------------------------------------------------------------------
__device__ __forceinline__ void na_tile(short* lds, const short* __restrict__ qkv,
                                        short* __restrict__ attn,
                                        int x0, int y0, int head)
{
    short* Ksh = lds;
    short* Vsh = lds + KSLOT * LDK;

    const int tid = threadIdx.x, lane = tid & 63, w = tid >> 6;
    const int rs  = min(max(y0 - 3, 0), HH - 7);
    const int wsx = x0 - 3;
    const short* Qp = qkv + (size_t)head * NPIX * HDIM;
    const short* Kp = qkv + (size_t)(NHEAD + head) * NPIX * HDIM;
    const short* Vp = qkv + (size_t)(2 * NHEAD + head) * NPIX * HDIM;

    for (int idx = tid; idx < 880; idx += 256) {
        int g = idx & 3, rc = idx >> 2;
        int i = rc / 22, c = rc - i * 22;
        int yy = rs + i, xx = wsx + c;
        if (yy < HH && (unsigned)xx < WW)
            *(short8v*)&Ksh[(i * 24 + c) * LDK + g * 8] =
                *(const short8v*)(Kp + (size_t)(yy * WW + xx) * HDIM + g * 8);
    }
    for (int idx = tid; idx < 264; idx += 256) {
        int g = idx & 3, q2 = idx >> 2;
        int i = q2 / 6, cq = q2 - i * 6;
        int yy = rs + i;
        short8v vv[4];
#pragma unroll
        for (int j = 0; j < 4; ++j) {
            int c = cq * 4 + j, xx = wsx + c;
            if (yy < HH && c < 22 && (unsigned)xx < WW)
                vv[j] = *(const short8v*)(Vp + (size_t)(yy * WW + xx) * HDIM + g * 8);
            else {
                short8v z = {0,0,0,0,0,0,0,0};
                vv[j] = z;
            }
        }
#pragma unroll
        for (int jd = 0; jd < 8; ++jd) {
            short4v s4 = {vv[0][jd], vv[1][jd], vv[2][jd], vv[3][jd]};
            *(short4v*)&Vsh[(g * 8 + jd) * VSLOT + i * 24 + cq * 4] = s4;
        }
    }

    const int l15 = lane & 15, l4 = lane >> 4;
    const int y = y0 + w;
    short8v qf = *(const short8v*)(Qp + (size_t)(y * WW + x0 + l15) * HDIM + l4 * 8);
    __syncthreads();

    const int wbase = (min(max(y - 3, 0), HH - 7) - rs) * 24;

    f32x4 sacc[11];
#pragma unroll
    for (int kc = 0; kc < 11; ++kc) {
        short8v kf = *(const short8v*)&Ksh[(wbase + kc * 16 + l15) * LDK + l4 * 8];
        f32x4 z = {0.f, 0.f, 0.f, 0.f};
        sacc[kc] = __builtin_amdgcn_mfma_f32_16x16x32_bf16(kf, qf, z, 0, 0, 0);
    }

    const int xq = x0 + l15;
    const int cw = min(max(xq - 3, 0), WW - 7) - wsx;
    const float scale = 0.17677669529663687f;
    float lsum = 0.f;
#pragma unroll
    for (int kc = 0; kc < 11; ++kc) {
#pragma unroll
        for (int r = 0; r < 4; ++r) {
            int kl = kc * 16 + l4 * 4 + r;
            int row = kl / 24;
            int c = kl - row * 24;
            bool valid = (row < 7) && (c >= cw) && (c <= cw + 6);
            float e = valid ? __expf(sacc[kc][r] * scale) : 0.f;
            sacc[kc][r] = e;
            lsum += e;
        }
    }
    lsum += __shfl_xor(lsum, 16);
    lsum += __shfl_xor(lsum, 32);
    const float inv = 1.0f / lsum;

    short4v pf[12];
#pragma unroll
    for (int kc = 0; kc < 11; ++kc) {
        short4v pk;
#pragma unroll
        for (int r = 0; r < 4; ++r) pk[r] = f2bf(sacc[kc][r] * inv);
        pf[kc] = pk;
    }
    pf[11] = (short4v){0, 0, 0, 0};

    const int src0 = ((l4 & 1) << 5) + l15;
    const int src1 = src0 + 16;
    const bool hi = (l4 & 2) != 0;
    f32x4 oacc[2];
    oacc[0] = (f32x4){0.f, 0.f, 0.f, 0.f};
    oacc[1] = (f32x4){0.f, 0.f, 0.f, 0.f};
#pragma unroll
    for (int kc2 = 0; kc2 < 6; ++kc2) {
        int lo0 = ((const int*)&pf[2 * kc2])[0];
        int lo1 = ((const int*)&pf[2 * kc2])[1];
        int hi0 = ((const int*)&pf[2 * kc2 + 1])[0];
        int hi1 = ((const int*)&pf[2 * kc2 + 1])[1];
        int a0 = __shfl(lo0, src0), a1 = __shfl(lo1, src0);
        int a2 = __shfl(lo0, src1), a3 = __shfl(lo1, src1);
        int b0 = __shfl(hi0, src0), b1 = __shfl(hi1, src0);
        int b2 = __shfl(hi0, src1), b3 = __shfl(hi1, src1);
        int w0 = hi ? b0 : a0, w1 = hi ? b1 : a1;
        int w2 = hi ? b2 : a2, w3 = hi ? b3 : a3;
        int wv[4] = {w0, w1, w2, w3};
        short8v bfrag = *(const short8v*)wv;
#pragma unroll
        for (int nc = 0; nc < 2; ++nc) {
            short8v vf = *(const short8v*)&Vsh[(nc * 16 + l15) * VSLOT
                                               + wbase + kc2 * 32 + l4 * 8];
            oacc[nc] = __builtin_amdgcn_mfma_f32_16x16x32_bf16(vf, bfrag, oacc[nc], 0, 0, 0);
        }
    }

    short* op = attn + (size_t)(y * WW + x0 + l15) * CC + head * HDIM;
#pragma unroll
    for (int nc = 0; nc < 2; ++nc) {
        short4v o;
#pragma unroll
        for (int r = 0; r < 4; ++r) o[r] = f2bf(oacc[nc][r]);
        *(short4v*)(op + nc * 16 + l4 * 4) = o;
    }
}

// ---------------------------------------------------------------------------
// Fused pipeline, 1024 blocks (all phases <= 1 tile per block).
// ---------------------------------------------------------------------------
__global__ __launch_bounds__(256, 4)
void fused(const float* __restrict__ x, const float* __restrict__ w_qkv,
           const float* __restrict__ b_qkv, const float* __restrict__ w_proj,
           const float* __restrict__ b_proj, float* __restrict__ out,
           short* __restrict__ wq_t, short* __restrict__ wp_t,
           short* __restrict__ qkv_r, short* __restrict__ attn_bf, u32* syncb)
{
    __shared__ f32x4 shq[2296];      // 36736 B, 16B-aligned
    short* sh = (short*)shq;
    const int bid = blockIdx.x;

    // phase 0: weight transposes (256 units)
    if (bid < 256)
        prep_unit((float*)shq, bid, w_qkv, w_proj, wq_t, wp_t);
    grid_sync(syncb, 1, bid);

    // phase 1: QKV GEMM, 768 tiles of 64x128
    if (bid < 768)
        qkv_tile(sh, x, wq_t, b_qkv, qkv_r, (bid & 127) * 64, (bid >> 7) * 128);
    grid_sync(syncb, 2, bid);

    // phase 2: neighborhood attention, 1024 tiles, 1:1
    na_tile(sh, qkv_r, attn_bf, (bid & 7) * 16, ((bid >> 3) & 15) * 4, bid >> 7);
    grid_sync(syncb, 3, bid);

    // phase 3: proj GEMM, 256 tiles of 64x128
    if (bid < 256)
        proj_tile(sh, attn_bf, wp_t, b_proj, out, (bid & 127) * 64, (bid >> 7) * 128);
}

// ---------------------------------------------------------------------------
extern "C" void kernel_launch(void* const* d_in, const int* in_sizes, int n_in,
                              void* d_out, int out_size, void* d_ws, size_t ws_size,
                              hipStream_t stream)
{
    const float* x      = (const float*)d_in[0];
    const float* w_qkv  = (const float*)d_in[1];
    const float* b_qkv  = (const float*)d_in[2];
    const float* w_proj = (const float*)d_in[3];
    const float* b_proj = (const float*)d_in[4];
    float* out = (float*)d_out;

    char* ws = (char*)d_ws;
    short* qkv_r   = (short*)ws;                    // 24 planes x 8192 x 32 bf16 = 12 MB
    short* attn_bf = (short*)(ws + 12582912);       // 8192x256 bf16 = 4 MB
    short* wq_t    = (short*)(ws + 16777216);       // 768x256 bf16
    short* wp_t    = (short*)(ws + 17170432);       // 256x256 bf16
    u32*   syncb   = (u32*)(ws + 17301504);         // 17 x 128B barrier state

    hipMemsetAsync(syncb, 0, 2176, stream);         // zero barrier state each launch
    fused<<<dim3(NBLK), dim3(256), 0, stream>>>(
        x, w_qkv, b_qkv, w_proj, b_proj, out,
        wq_t, wp_t, qkv_r, attn_bf, syncb);
}

// Round 11
// 56.404 us; speedup vs baseline: 3.0932x; 3.0932x over previous
//
#include <hip/hip_runtime.h>
#include <cmath>

// B=1, H=64, W=128, C=256, 8 heads x 32 dim, 7x7 window.
#define HH 64
#define WW 128
#define CC 256
#define NHEAD 8
#define HDIM 32
#define NPIX (HH*WW)       // 8192
#define QKV_N (3*CC)       // 768

#define KSLOT 248
#define LDK   40
#define VSLOT 264

typedef __attribute__((ext_vector_type(8))) short short8v;  // 8 bf16
typedef __attribute__((ext_vector_type(4))) short short4v;  // 4 bf16
typedef __attribute__((ext_vector_type(4))) float f32x4;
typedef unsigned int u32;

__device__ __forceinline__ short f2bf(float f) {
    unsigned int u = __builtin_bit_cast(unsigned int, f);
    u += 0x7fffu + ((u >> 16) & 1u);
    return (short)(u >> 16);
}

// ---------------------------------------------------------------------------
// QKV GEMM, zero-LDS, zero-barrier: qkv_planes = x * w_qkv + b_qkv.
// BM=128 BN=64, grid (64,12)=768 blocks, 4 waves 2x2 (WM=64, WN=32).
// B-frags (w_qkv fp32 [256][768], untransposed) loaded DIRECTLY to registers:
//   lane(l15=n, l4) frag[fn][t][j] = W[t*32+l4*8+j][bn+wn0+fn*16+l15]
//   -> 8 scalar loads/frag, 64B-coalesced across l15, L2-resident source.
//   16 frags live = 64 VGPR. No wq_t, no prep kernel, no transpose anywhere.
// A-frags direct from global fp32 x (2 dwordx4/frag) + f2bf in reg -- same
// rounding point as the old x_bf prep => bit-identical output.
// A-row re-reads across the 12 bn-blocks hit the same XCD's L2 (grid-x = 64,
// 64 % 8 == 0 -> all sharers land on one XCD).
// ---------------------------------------------------------------------------
__global__ __launch_bounds__(256)
void gemm_qkv(const float* __restrict__ A, const float* __restrict__ W,
              const float* __restrict__ bias, short* __restrict__ Cp)
{
    const int tid = threadIdx.x, lane = tid & 63, wave = tid >> 6;
    const int bm = blockIdx.x * 128, bn = blockIdx.y * 64;
    const int wm0 = (wave >> 1) * 64, wn0 = (wave & 1) * 32;
    const int l15 = lane & 15, l4 = lane >> 4;

    // ---- B-frags: 2 fn x 8 t ----
    short8v bbr[2][8];
#pragma unroll
    for (int fn = 0; fn < 2; ++fn) {
        const int n = bn + wn0 + fn * 16 + l15;
#pragma unroll
        for (int t = 0; t < 8; ++t) {
            const float* wp = W + (size_t)(t * 32 + l4 * 8) * QKV_N + n;
            short8v b;
#pragma unroll
            for (int j = 0; j < 8; ++j)
                b[j] = f2bf(wp[(size_t)j * QKV_N]);
            bbr[fn][t] = b;
        }
    }

    f32x4 acc[4][2];
#pragma unroll
    for (int i = 0; i < 4; ++i)
#pragma unroll
        for (int j = 0; j < 2; ++j) acc[i][j] = (f32x4){0.f, 0.f, 0.f, 0.f};

#pragma unroll
    for (int t = 0; t < 8; ++t) {
        short8v af[4];
#pragma unroll
        for (int fm = 0; fm < 4; ++fm) {
            const float* p = A + (size_t)(bm + wm0 + fm * 16 + l15) * CC
                             + t * 32 + l4 * 8;
            float4 a0 = *(const float4*)p;
            float4 a1 = *(const float4*)(p + 4);
            short8v w;
            w[0] = f2bf(a0.x); w[1] = f2bf(a0.y); w[2] = f2bf(a0.z); w[3] = f2bf(a0.w);
            w[4] = f2bf(a1.x); w[5] = f2bf(a1.y); w[6] = f2bf(a1.z); w[7] = f2bf(a1.w);
            af[fm] = w;
        }
#pragma unroll
        for (int fm = 0; fm < 4; ++fm)
#pragma unroll
            for (int fn = 0; fn < 2; ++fn)
                acc[fm][fn] = __builtin_amdgcn_mfma_f32_16x16x32_bf16(
                    af[fm], bbr[fn][t], acc[fm][fn], 0, 0, 0);
    }

    // ---- epilogue: plane layout [24][NPIX][32] (verbatim R9 math) ----
    const int col0 = bn + wn0 + l15;
    const int row0 = bm + wm0 + l4 * 4;
#pragma unroll
    for (int fn = 0; fn < 2; ++fn) {
        const int cc = col0 + fn * 16;
        const float bv = bias[cc];
#pragma unroll
        for (int fm = 0; fm < 4; ++fm)
#pragma unroll
            for (int r = 0; r < 4; ++r) {
                const int rr = row0 + fm * 16 + r;
                Cp[((size_t)(cc >> 5) * NPIX + rr) * HDIM + (cc & 31)] =
                    f2bf(acc[fm][fn][r] + bv);
            }
    }
}

// ---------------------------------------------------------------------------
// proj GEMM, zero-LDS, zero-barrier: out = attn_bf * w_proj + b_proj (fp32).
// BM=64 BN=64, grid (128,4)=512 blocks, 4 waves 2x2 (WM=32, WN=32).
// A bf16 direct (1 dwordx4/frag); B (w_proj fp32 [256][256]) direct to regs.
// ---------------------------------------------------------------------------
__global__ __launch_bounds__(256)
void gemm_proj(const short* __restrict__ A, const float* __restrict__ W,
               const float* __restrict__ bias, float* __restrict__ C)
{
    const int tid = threadIdx.x, lane = tid & 63, wave = tid >> 6;
    const int bm = blockIdx.x * 64, bn = blockIdx.y * 64;
    const int wm0 = (wave >> 1) * 32, wn0 = (wave & 1) * 32;
    const int l15 = lane & 15, l4 = lane >> 4;

    short8v bbr[2][8];
#pragma unroll
    for (int fn = 0; fn < 2; ++fn) {
        const int n = bn + wn0 + fn * 16 + l15;
#pragma unroll
        for (int t = 0; t < 8; ++t) {
            const float* wp = W + (size_t)(t * 32 + l4 * 8) * CC + n;
            short8v b;
#pragma unroll
            for (int j = 0; j < 8; ++j)
                b[j] = f2bf(wp[(size_t)j * CC]);
            bbr[fn][t] = b;
        }
    }

    f32x4 acc[2][2];
#pragma unroll
    for (int i = 0; i < 2; ++i)
#pragma unroll
        for (int j = 0; j < 2; ++j) acc[i][j] = (f32x4){0.f, 0.f, 0.f, 0.f};

#pragma unroll
    for (int t = 0; t < 8; ++t) {
        short8v af[2];
#pragma unroll
        for (int fm = 0; fm < 2; ++fm)
            af[fm] = *(const short8v*)(A + (size_t)(bm + wm0 + fm * 16 + l15) * CC
                                       + t * 32 + l4 * 8);
#pragma unroll
        for (int fm = 0; fm < 2; ++fm)
#pragma unroll
            for (int fn = 0; fn < 2; ++fn)
                acc[fm][fn] = __builtin_amdgcn_mfma_f32_16x16x32_bf16(
                    af[fm], bbr[fn][t], acc[fm][fn], 0, 0, 0);
    }

    const int col0 = bn + wn0 + l15;
    const int row0 = bm + wm0 + l4 * 4;
#pragma unroll
    for (int fn = 0; fn < 2; ++fn) {
        const float bv = bias[col0 + fn * 16];
#pragma unroll
        for (int fm = 0; fm < 2; ++fm)
#pragma unroll
            for (int r = 0; r < 4; ++r)
                C[(size_t)(row0 + fm * 16 + r) * CC + col0 + fn * 16] =
                    acc[fm][fn][r] + bv;
    }
}

// ---------------------------------------------------------------------------
// Neighborhood attention (R9 body verbatim; qkv in plane layout
// [24][NPIX][32] so staging reads are 1KB-contiguous per wave).
// ---------------------------------------------------------------------------
__global__ __launch_bounds__(256)
void na_mfma(const short* __restrict__ qkv, short* __restrict__ attn)
{
    __shared__ short Ksh[KSLOT * LDK];   // 19840 B
    __shared__ short Vsh[32 * VSLOT];    // 16896 B  [d][slot]

    const int x0 = blockIdx.x * 16;
    const int y0 = blockIdx.y * 4;
    const int head = blockIdx.z;
    const int tid = threadIdx.x, lane = tid & 63, w = tid >> 6;
    const int rs  = min(max(y0 - 3, 0), HH - 7);
    const int wsx = x0 - 3;
    const short* Qp = qkv + (size_t)head * NPIX * HDIM;
    const short* Kp = qkv + (size_t)(NHEAD + head) * NPIX * HDIM;
    const short* Vp = qkv + (size_t)(2 * NHEAD + head) * NPIX * HDIM;

    for (int idx = tid; idx < 880; idx += 256) {
        int g = idx & 3, rc = idx >> 2;
        int i = rc / 22, c = rc - i * 22;
        int yy = rs + i, xx = wsx + c;
        if (yy < HH && (unsigned)xx < WW)
            *(short8v*)&Ksh[(i * 24 + c) * LDK + g * 8] =
                *(const short8v*)(Kp + (size_t)(yy * WW + xx) * HDIM + g * 8);
    }
    for (int idx = tid; idx < 264; idx += 256) {
        int g = idx & 3, q2 = idx >> 2;
        int i = q2 / 6, cq = q2 - i * 6;
        int yy = rs + i;
        short8v vv[4];
#pragma unroll
        for (int j = 0; j < 4; ++j) {
            int c = cq * 4 + j, xx = wsx + c;
            if (yy < HH && c < 22 && (unsigned)xx < WW)
                vv[j] = *(const short8v*)(Vp + (size_t)(yy * WW + xx) * HDIM + g * 8);
            else {
                short8v z = {0,0,0,0,0,0,0,0};
                vv[j] = z;
            }
        }
#pragma unroll
        for (int jd = 0; jd < 8; ++jd) {
            short4v s4 = {vv[0][jd], vv[1][jd], vv[2][jd], vv[3][jd]};
            *(short4v*)&Vsh[(g * 8 + jd) * VSLOT + i * 24 + cq * 4] = s4;
        }
    }

    const int l15 = lane & 15, l4 = lane >> 4;
    const int y = y0 + w;
    short8v qf = *(const short8v*)(Qp + (size_t)(y * WW + x0 + l15) * HDIM + l4 * 8);
    __syncthreads();

    const int wbase = (min(max(y - 3, 0), HH - 7) - rs) * 24;

    f32x4 sacc[11];
#pragma unroll
    for (int kc = 0; kc < 11; ++kc) {
        short8v kf = *(const short8v*)&Ksh[(wbase + kc * 16 + l15) * LDK + l4 * 8];
        f32x4 z = {0.f, 0.f, 0.f, 0.f};
        sacc[kc] = __builtin_amdgcn_mfma_f32_16x16x32_bf16(kf, qf, z, 0, 0, 0);
    }

    const int xq = x0 + l15;
    const int cw = min(max(xq - 3, 0), WW - 7) - wsx;
    const float scale = 0.17677669529663687f;
    float lsum = 0.f;
#pragma unroll
    for (int kc = 0; kc < 11; ++kc) {
#pragma unroll
        for (int r = 0; r < 4; ++r) {
            int kl = kc * 16 + l4 * 4 + r;
            int row = kl / 24;
            int c = kl - row * 24;
            bool valid = (row < 7) && (c >= cw) && (c <= cw + 6);
            float e = valid ? __expf(sacc[kc][r] * scale) : 0.f;
            sacc[kc][r] = e;
            lsum += e;
        }
    }
    lsum += __shfl_xor(lsum, 16);
    lsum += __shfl_xor(lsum, 32);
    const float inv = 1.0f / lsum;

    short4v pf[12];
#pragma unroll
    for (int kc = 0; kc < 11; ++kc) {
        short4v pk;
#pragma unroll
        for (int r = 0; r < 4; ++r) pk[r] = f2bf(sacc[kc][r] * inv);
        pf[kc] = pk;
    }
    pf[11] = (short4v){0, 0, 0, 0};

    const int src0 = ((l4 & 1) << 5) + l15;
    const int src1 = src0 + 16;
    const bool hi = (l4 & 2) != 0;
    f32x4 oacc[2];
    oacc[0] = (f32x4){0.f, 0.f, 0.f, 0.f};
    oacc[1] = (f32x4){0.f, 0.f, 0.f, 0.f};
#pragma unroll
    for (int kc2 = 0; kc2 < 6; ++kc2) {
        int lo0 = ((const int*)&pf[2 * kc2])[0];
        int lo1 = ((const int*)&pf[2 * kc2])[1];
        int hi0 = ((const int*)&pf[2 * kc2 + 1])[0];
        int hi1 = ((const int*)&pf[2 * kc2 + 1])[1];
        int a0 = __shfl(lo0, src0), a1 = __shfl(lo1, src0);
        int a2 = __shfl(lo0, src1), a3 = __shfl(lo1, src1);
        int b0 = __shfl(hi0, src0), b1 = __shfl(hi1, src0);
        int b2 = __shfl(hi0, src1), b3 = __shfl(hi1, src1);
        int w0 = hi ? b0 : a0, w1 = hi ? b1 : a1;
        int w2 = hi ? b2 : a2, w3 = hi ? b3 : a3;
        int wv[4] = {w0, w1, w2, w3};
        short8v bfrag = *(const short8v*)wv;
#pragma unroll
        for (int nc = 0; nc < 2; ++nc) {
            short8v vf = *(const short8v*)&Vsh[(nc * 16 + l15) * VSLOT
                                               + wbase + kc2 * 32 + l4 * 8];
            oacc[nc] = __builtin_amdgcn_mfma_f32_16x16x32_bf16(vf, bfrag, oacc[nc], 0, 0, 0);
        }
    }

    short* op = attn + (size_t)(y * WW + x0 + l15) * CC + head * HDIM;
#pragma unroll
    for (int nc = 0; nc < 2; ++nc) {
        short4v o;
#pragma unroll
        for (int r = 0; r < 4; ++r) o[r] = f2bf(oacc[nc][r]);
        *(short4v*)(op + nc * 16 + l4 * 4) = o;
    }
}

// ---------------------------------------------------------------------------
extern "C" void kernel_launch(void* const* d_in, const int* in_sizes, int n_in,
                              void* d_out, int out_size, void* d_ws, size_t ws_size,
                              hipStream_t stream)
{
    const float* x      = (const float*)d_in[0];
    const float* w_qkv  = (const float*)d_in[1];
    const float* b_qkv  = (const float*)d_in[2];
    const float* w_proj = (const float*)d_in[3];
    const float* b_proj = (const float*)d_in[4];
    float* out = (float*)d_out;

    char* ws = (char*)d_ws;
    short* qkv_r   = (short*)ws;                    // 24 planes x 8192 x 32 bf16 = 12 MB
    short* attn_bf = (short*)(ws + 12582912);       // 8192x256 bf16 = 4 MB

    // QKV: M=8192, N=768, K=256 -> bf16 planes (no prep, no LDS, no barriers)
    gemm_qkv<<<dim3(NPIX / 128, QKV_N / 64), dim3(256), 0, stream>>>(
        x, w_qkv, b_qkv, qkv_r);

    // attention
    na_mfma<<<dim3(WW / 16, HH / 4, NHEAD), dim3(256), 0, stream>>>(qkv_r, attn_bf);

    // proj: M=8192, N=256, K=256 -> fp32 out (no LDS, no barriers)
    gemm_proj<<<dim3(NPIX / 64, CC / 64), dim3(256), 0, stream>>>(
        attn_bf, w_proj, b_proj, out);
}

// Round 12
// 44.860 us; speedup vs baseline: 3.8892x; 1.2573x over previous
//
#include <hip/hip_runtime.h>
#include <cmath>

// B=1, H=64, W=128, C=256, 8 heads x 32 dim, 7x7 window.
#define HH 64
#define WW 128
#define CC 256
#define NHEAD 8
#define HDIM 32
#define NPIX (HH*WW)       // 8192
#define QKV_N (3*CC)       // 768

#define KSLOT 248
#define LDK   40
#define VSLOT 264

typedef __attribute__((ext_vector_type(8))) short short8v;  // 8 bf16
typedef __attribute__((ext_vector_type(4))) short short4v;  // 4 bf16
typedef __attribute__((ext_vector_type(4))) float f32x4;
typedef unsigned int u32;

__device__ __forceinline__ short f2bf(float f) {
    unsigned int u = __builtin_bit_cast(unsigned int, f);
    u += 0x7fffu + ((u >> 16) & 1u);
    return (short)(u >> 16);
}

// ---------------------------------------------------------------------------
// QKV GEMM, 3-node pipeline node 1: qkv_planes = x(fp32) * w_qkv(fp32) + b.
// BM=128 BN=64 BK=32, grid (64,12)=768 blocks, 4 waves 2x2 (WM=64, WN=32).
// A: fp32 x reg-staged -> f2bf -> LDS (padded 80B rows), double-buffered.
// B: w_qkv [k][n] fp32 transposed AT STAGE TIME: per k-step each thread does
//    4 coalesced dwordx2 loads (4 k-rows x 2 n) and 2 ds_write_b64 of
//    k-contiguous short4 into Bs[n][k] (80B-padded rows). No prep node, no
//    wq_t buffer. f2bf rounding points identical to R6's prep => bit-identical.
// One barrier per k-step (write buf^1 after barrier t; read buf^1 after
// barrier t+1).
// ---------------------------------------------------------------------------
__global__ __launch_bounds__(256)
void gemm_qkv(const float* __restrict__ x, const float* __restrict__ W,
              const float* __restrict__ bias, short* __restrict__ Cp)
{
    __shared__ short As[2][128 * LDK];   // 20480 B
    __shared__ short Bs[2][64 * LDK];    // 10240 B

    const int tid = threadIdx.x, lane = tid & 63, wave = tid >> 6;
    const int bm = blockIdx.x * 128, bn = blockIdx.y * 64;
    const int wm0 = (wave >> 1) * 64, wn0 = (wave & 1) * 32;
    const int l15 = lane & 15, l4 = lane >> 4;

    // A staging: row = tid>>1 (0..127), ko = (tid&1)*16
    const int arow = tid >> 1, ako = (tid & 1) * 16;
    // B staging: k0 = (tid>>5)*4, n0 = (tid&31)*2
    const int bk0 = (tid >> 5) * 4, bn0 = (tid & 31) * 2;

    float4 a0, a1, a2, a3;
    float2 w0, w1, w2, w3;

    auto loadA = [&](int t) {
        const float* p = x + (size_t)(bm + arow) * CC + t * 32 + ako;
        a0 = *(const float4*)p;       a1 = *(const float4*)(p + 4);
        a2 = *(const float4*)(p + 8); a3 = *(const float4*)(p + 12);
    };
    auto loadB = [&](int t) {
        const float* p = W + (size_t)(t * 32 + bk0) * QKV_N + bn + bn0;
        w0 = *(const float2*)p;
        w1 = *(const float2*)(p + QKV_N);
        w2 = *(const float2*)(p + 2 * QKV_N);
        w3 = *(const float2*)(p + 3 * QKV_N);
    };
    auto writeAB = [&](int buf) {
        short8v v0, v1;
        v0[0] = f2bf(a0.x); v0[1] = f2bf(a0.y); v0[2] = f2bf(a0.z); v0[3] = f2bf(a0.w);
        v0[4] = f2bf(a1.x); v0[5] = f2bf(a1.y); v0[6] = f2bf(a1.z); v0[7] = f2bf(a1.w);
        v1[0] = f2bf(a2.x); v1[1] = f2bf(a2.y); v1[2] = f2bf(a2.z); v1[3] = f2bf(a2.w);
        v1[4] = f2bf(a3.x); v1[5] = f2bf(a3.y); v1[6] = f2bf(a3.z); v1[7] = f2bf(a3.w);
        *(short8v*)&As[buf][arow * LDK + ako] = v0;
        *(short8v*)&As[buf][arow * LDK + ako + 8] = v1;
        const float wf[4][2] = {{w0.x, w0.y}, {w1.x, w1.y}, {w2.x, w2.y}, {w3.x, w3.y}};
#pragma unroll
        for (int i = 0; i < 2; ++i) {
            short4v s = {f2bf(wf[0][i]), f2bf(wf[1][i]), f2bf(wf[2][i]), f2bf(wf[3][i])};
            *(short4v*)&Bs[buf][(bn0 + i) * LDK + bk0] = s;
        }
    };

    f32x4 acc[4][2];
#pragma unroll
    for (int i = 0; i < 4; ++i)
#pragma unroll
        for (int j = 0; j < 2; ++j) acc[i][j] = (f32x4){0.f, 0.f, 0.f, 0.f};

    loadA(0); loadB(0);
    writeAB(0);
    loadA(1); loadB(1);

    for (int t = 0; t < 8; ++t) {
        const int cur = t & 1;
        __syncthreads();                       // buf[cur] complete; prev reads done
        if (t + 1 < 8) {
            writeAB(cur ^ 1);                  // stage t+1 into the other buffer
            if (t + 2 < 8) { loadA(t + 2); loadB(t + 2); }
        }
        short8v af[4], bf[2];
#pragma unroll
        for (int fm = 0; fm < 4; ++fm)
            af[fm] = *(const short8v*)&As[cur][(wm0 + fm * 16 + l15) * LDK + l4 * 8];
#pragma unroll
        for (int fn = 0; fn < 2; ++fn)
            bf[fn] = *(const short8v*)&Bs[cur][(wn0 + fn * 16 + l15) * LDK + l4 * 8];
#pragma unroll
        for (int fm = 0; fm < 4; ++fm)
#pragma unroll
            for (int fn = 0; fn < 2; ++fn)
                acc[fm][fn] = __builtin_amdgcn_mfma_f32_16x16x32_bf16(
                    af[fm], bf[fn], acc[fm][fn], 0, 0, 0);
    }

    // plane layout [24][NPIX][32] for na staging
    const int col0 = bn + wn0 + l15;
    const int row0 = bm + wm0 + l4 * 4;
#pragma unroll
    for (int fn = 0; fn < 2; ++fn) {
        const int cc = col0 + fn * 16;
        const float bv = bias[cc];
#pragma unroll
        for (int fm = 0; fm < 4; ++fm)
#pragma unroll
            for (int r = 0; r < 4; ++r) {
                const int rr = row0 + fm * 16 + r;
                Cp[((size_t)(cc >> 5) * NPIX + rr) * HDIM + (cc & 31)] =
                    f2bf(acc[fm][fn][r] + bv);
            }
    }
}

// ---------------------------------------------------------------------------
// proj GEMM, node 3: out = attn_bf(bf16) * w_proj(fp32) + b_proj (fp32 out).
// BM=64 BN=128 BK=32, grid (128,2)=256 blocks, 4 waves 2x2 (WM=32, WN=64).
// A: gload_lds double-buffered, linear dest (R6-proven path).
// B: w_proj transposed at stage time (4 coalesced dwordx4 + 4 ds_write_b64
//    into 80B-padded rows). No wp_t, no prep.
// ---------------------------------------------------------------------------
__global__ __launch_bounds__(256)
void gemm_proj(const short* __restrict__ A, const float* __restrict__ W,
               const float* __restrict__ bias, float* __restrict__ C)
{
    __shared__ short As[2][64 * 32];     // 8192 B, linear (gload_lds dest)
    __shared__ short Bs[2][128 * LDK];   // 20480 B, padded rows

    const int tid = threadIdx.x, lane = tid & 63, wave = tid >> 6;
    const int bm = blockIdx.x * 64, bn = blockIdx.y * 128;
    const int wm0 = (wave >> 1) * 32, wn0 = (wave & 1) * 64;
    const int l15 = lane & 15, l4 = lane >> 4;

    const int garow = tid >> 2, gagr = tid & 3;      // A granule mapping
    const int bk0 = (tid >> 5) * 4, bn0 = (tid & 31) * 4;   // B transpose mapping

    float4 w0, w1, w2, w3;

    auto gloadA = [&](int buf, int t) {
        __builtin_amdgcn_global_load_lds(
            (const __attribute__((address_space(1))) u32*)
                (A + (size_t)(bm + garow) * CC + t * 32 + gagr * 8),
            (__attribute__((address_space(3))) u32*)&As[buf][tid * 8], 16, 0, 0);
    };
    auto loadB = [&](int t) {
        const float* p = W + (size_t)(t * 32 + bk0) * CC + bn + bn0;
        w0 = *(const float4*)p;
        w1 = *(const float4*)(p + CC);
        w2 = *(const float4*)(p + 2 * CC);
        w3 = *(const float4*)(p + 3 * CC);
    };
    auto writeB = [&](int buf) {
        const float wf[4][4] = {{w0.x, w0.y, w0.z, w0.w}, {w1.x, w1.y, w1.z, w1.w},
                                {w2.x, w2.y, w2.z, w2.w}, {w3.x, w3.y, w3.z, w3.w}};
#pragma unroll
        for (int i = 0; i < 4; ++i) {
            short4v s = {f2bf(wf[0][i]), f2bf(wf[1][i]), f2bf(wf[2][i]), f2bf(wf[3][i])};
            *(short4v*)&Bs[buf][(bn0 + i) * LDK + bk0] = s;
        }
    };

    f32x4 acc[2][4];
#pragma unroll
    for (int i = 0; i < 2; ++i)
#pragma unroll
        for (int j = 0; j < 4; ++j) acc[i][j] = (f32x4){0.f, 0.f, 0.f, 0.f};

    gloadA(0, 0);
    loadB(0); writeB(0);
    loadB(1);

    for (int t = 0; t < 8; ++t) {
        const int cur = t & 1;
        __syncthreads();                 // buf[cur] landed; prev reads done
        if (t + 1 < 8) {
            gloadA(cur ^ 1, t + 1);
            writeB(cur ^ 1);
            if (t + 2 < 8) loadB(t + 2);
        }
        short8v af[2], bf[4];
#pragma unroll
        for (int fm = 0; fm < 2; ++fm)
            af[fm] = *(const short8v*)&As[cur][(wm0 + fm * 16 + l15) * 32 + l4 * 8];
#pragma unroll
        for (int fn = 0; fn < 4; ++fn)
            bf[fn] = *(const short8v*)&Bs[cur][(wn0 + fn * 16 + l15) * LDK + l4 * 8];
#pragma unroll
        for (int fm = 0; fm < 2; ++fm)
#pragma unroll
            for (int fn = 0; fn < 4; ++fn)
                acc[fm][fn] = __builtin_amdgcn_mfma_f32_16x16x32_bf16(
                    af[fm], bf[fn], acc[fm][fn], 0, 0, 0);
    }

    const int col0 = bn + wn0 + l15;
    const int row0 = bm + wm0 + l4 * 4;
#pragma unroll
    for (int fn = 0; fn < 4; ++fn) {
        const float bv = bias[col0 + fn * 16];
#pragma unroll
        for (int fm = 0; fm < 2; ++fm)
#pragma unroll
            for (int r = 0; r < 4; ++r)
                C[(size_t)(row0 + fm * 16 + r) * CC + col0 + fn * 16] =
                    acc[fm][fn][r] + bv;
    }
}

// ---------------------------------------------------------------------------
// Neighborhood attention, node 2 (R11 body verbatim; plane-layout qkv).
// ---------------------------------------------------------------------------
__global__ __launch_bounds__(256)
void na_mfma(const short* __restrict__ qkv, short* __restrict__ attn)
{
    __shared__ short Ksh[KSLOT * LDK];   // 19840 B
    __shared__ short Vsh[32 * VSLOT];    // 16896 B  [d][slot]

    const int x0 = blockIdx.x * 16;
    const int y0 = blockIdx.y * 4;
    const int head = blockIdx.z;
    const int tid = threadIdx.x, lane = tid & 63, w = tid >> 6;
    const int rs  = min(max(y0 - 3, 0), HH - 7);
    const int wsx = x0 - 3;
    const short* Qp = qkv + (size_t)head * NPIX * HDIM;
    const short* Kp = qkv + (size_t)(NHEAD + head) * NPIX * HDIM;
    const short* Vp = qkv + (size_t)(2 * NHEAD + head) * NPIX * HDIM;

    for (int idx = tid; idx < 880; idx += 256) {
        int g = idx & 3, rc = idx >> 2;
        int i = rc / 22, c = rc - i * 22;
        int yy = rs + i, xx = wsx + c;
        if (yy < HH && (unsigned)xx < WW)
            *(short8v*)&Ksh[(i * 24 + c) * LDK + g * 8] =
                *(const short8v*)(Kp + (size_t)(yy * WW + xx) * HDIM + g * 8);
    }
    for (int idx = tid; idx < 264; idx += 256) {
        int g = idx & 3, q2 = idx >> 2;
        int i = q2 / 6, cq = q2 - i * 6;
        int yy = rs + i;
        short8v vv[4];
#pragma unroll
        for (int j = 0; j < 4; ++j) {
            int c = cq * 4 + j, xx = wsx + c;
            if (yy < HH && c < 22 && (unsigned)xx < WW)
                vv[j] = *(const short8v*)(Vp + (size_t)(yy * WW + xx) * HDIM + g * 8);
            else {
                short8v z = {0,0,0,0,0,0,0,0};
                vv[j] = z;
            }
        }
#pragma unroll
        for (int jd = 0; jd < 8; ++jd) {
            short4v s4 = {vv[0][jd], vv[1][jd], vv[2][jd], vv[3][jd]};
            *(short4v*)&Vsh[(g * 8 + jd) * VSLOT + i * 24 + cq * 4] = s4;
        }
    }

    const int l15 = lane & 15, l4 = lane >> 4;
    const int y = y0 + w;
    short8v qf = *(const short8v*)(Qp + (size_t)(y * WW + x0 + l15) * HDIM + l4 * 8);
    __syncthreads();

    const int wbase = (min(max(y - 3, 0), HH - 7) - rs) * 24;

    f32x4 sacc[11];
#pragma unroll
    for (int kc = 0; kc < 11; ++kc) {
        short8v kf = *(const short8v*)&Ksh[(wbase + kc * 16 + l15) * LDK + l4 * 8];
        f32x4 z = {0.f, 0.f, 0.f, 0.f};
        sacc[kc] = __builtin_amdgcn_mfma_f32_16x16x32_bf16(kf, qf, z, 0, 0, 0);
    }

    const int xq = x0 + l15;
    const int cw = min(max(xq - 3, 0), WW - 7) - wsx;
    const float scale = 0.17677669529663687f;
    float lsum = 0.f;
#pragma unroll
    for (int kc = 0; kc < 11; ++kc) {
#pragma unroll
        for (int r = 0; r < 4; ++r) {
            int kl = kc * 16 + l4 * 4 + r;
            int row = kl / 24;
            int c = kl - row * 24;
            bool valid = (row < 7) && (c >= cw) && (c <= cw + 6);
            float e = valid ? __expf(sacc[kc][r] * scale) : 0.f;
            sacc[kc][r] = e;
            lsum += e;
        }
    }
    lsum += __shfl_xor(lsum, 16);
    lsum += __shfl_xor(lsum, 32);
    const float inv = 1.0f / lsum;

    short4v pf[12];
#pragma unroll
    for (int kc = 0; kc < 11; ++kc) {
        short4v pk;
#pragma unroll
        for (int r = 0; r < 4; ++r) pk[r] = f2bf(sacc[kc][r] * inv);
        pf[kc] = pk;
    }
    pf[11] = (short4v){0, 0, 0, 0};

    const int src0 = ((l4 & 1) << 5) + l15;
    const int src1 = src0 + 16;
    const bool hi = (l4 & 2) != 0;
    f32x4 oacc[2];
    oacc[0] = (f32x4){0.f, 0.f, 0.f, 0.f};
    oacc[1] = (f32x4){0.f, 0.f, 0.f, 0.f};
#pragma unroll
    for (int kc2 = 0; kc2 < 6; ++kc2) {
        int lo0 = ((const int*)&pf[2 * kc2])[0];
        int lo1 = ((const int*)&pf[2 * kc2])[1];
        int hi0 = ((const int*)&pf[2 * kc2 + 1])[0];
        int hi1 = ((const int*)&pf[2 * kc2 + 1])[1];
        int a0 = __shfl(lo0, src0), a1 = __shfl(lo1, src0);
        int a2 = __shfl(lo0, src1), a3 = __shfl(lo1, src1);
        int b0 = __shfl(hi0, src0), b1 = __shfl(hi1, src0);
        int b2 = __shfl(hi0, src1), b3 = __shfl(hi1, src1);
        int w0 = hi ? b0 : a0, w1 = hi ? b1 : a1;
        int w2 = hi ? b2 : a2, w3 = hi ? b3 : a3;
        int wv[4] = {w0, w1, w2, w3};
        short8v bfrag = *(const short8v*)wv;
#pragma unroll
        for (int nc = 0; nc < 2; ++nc) {
            short8v vf = *(const short8v*)&Vsh[(nc * 16 + l15) * VSLOT
                                               + wbase + kc2 * 32 + l4 * 8];
            oacc[nc] = __builtin_amdgcn_mfma_f32_16x16x32_bf16(vf, bfrag, oacc[nc], 0, 0, 0);
        }
    }

    short* op = attn + (size_t)(y * WW + x0 + l15) * CC + head * HDIM;
#pragma unroll
    for (int nc = 0; nc < 2; ++nc) {
        short4v o;
#pragma unroll
        for (int r = 0; r < 4; ++r) o[r] = f2bf(oacc[nc][r]);
        *(short4v*)(op + nc * 16 + l4 * 4) = o;
    }
}

// ---------------------------------------------------------------------------
extern "C" void kernel_launch(void* const* d_in, const int* in_sizes, int n_in,
                              void* d_out, int out_size, void* d_ws, size_t ws_size,
                              hipStream_t stream)
{
    const float* x      = (const float*)d_in[0];
    const float* w_qkv  = (const float*)d_in[1];
    const float* b_qkv  = (const float*)d_in[2];
    const float* w_proj = (const float*)d_in[3];
    const float* b_proj = (const float*)d_in[4];
    float* out = (float*)d_out;

    char* ws = (char*)d_ws;
    short* qkv_r   = (short*)ws;                    // 24 planes x 8192 x 32 bf16 = 12 MB
    short* attn_bf = (short*)(ws + 12582912);       // 8192x256 bf16 = 4 MB

    // QKV: M=8192, N=768, K=256 -> bf16 planes (fp32 inputs consumed directly)
    gemm_qkv<<<dim3(NPIX / 128, QKV_N / 64), dim3(256), 0, stream>>>(
        x, w_qkv, b_qkv, qkv_r);

    // attention
    na_mfma<<<dim3(WW / 16, HH / 4, NHEAD), dim3(256), 0, stream>>>(qkv_r, attn_bf);

    // proj: M=8192, N=256, K=256 -> fp32 out
    gemm_proj<<<dim3(NPIX / 64, CC / 128), dim3(256), 0, stream>>>(
        attn_bf, w_proj, b_proj, out);
}